// Round 3
// baseline (812.927 us; speedup 1.0000x reference)
//
#include <hip/hip_runtime.h>
#include <hip/hip_bf16.h>

#define NIN   128
#define NOUT  64
#define RANK  10
#define WLEN  101
#define TLEN  50000
#define TILE2 2048
#define NT2   25                  // ceil(50000/2048)
#define TPAD2 (NT2 * TILE2)       // 51200
#define TPADC 50176               // c-row length (98*512), stats/stores masked
#define XSLEN 2152                // LDS floats: p = g - tstart + 53, p in [0,2152)
#define KROW  208                 // floats per rank in Kpi: 26 j4-slots * 8

// 8 FMAs (re) + 8 FMAs (im) on one tap pair
#define RUN(KR, KI, X0, X1, X2, X3, X4, X5, X6, X7)                  \
    re[0] = fmaf((X0), (KR), re[0]); im[0] = fmaf((X0), (KI), im[0]); \
    re[1] = fmaf((X1), (KR), re[1]); im[1] = fmaf((X1), (KI), im[1]); \
    re[2] = fmaf((X2), (KR), re[2]); im[2] = fmaf((X2), (KI), im[2]); \
    re[3] = fmaf((X3), (KR), re[3]); im[3] = fmaf((X3), (KI), im[3]); \
    re[4] = fmaf((X4), (KR), re[4]); im[4] = fmaf((X4), (KI), im[4]); \
    re[5] = fmaf((X5), (KR), re[5]); im[5] = fmaf((X5), (KI), im[5]); \
    re[6] = fmaf((X6), (KR), re[6]); im[6] = fmaf((X6), (KI), im[6]); \
    re[7] = fmaf((X7), (KR), re[7]); im[7] = fmaf((X7), (KI), im[7]);

// One tap-block step: j = 4*J4 + jo. N = new (lowest) block, M = mid, O = old.
// Window floats w[0..11] = [N|M|O]; jo uses w[3+i-jo], i in [0,8).
#define CSTEP(J4, N, M, O) {                                                   \
    N = xs4[xbase - (J4)];                                                     \
    float4 kr = Kr[2 * (J4)];                                                  \
    float4 ki = Kr[2 * (J4) + 1];                                              \
    RUN(kr.x, ki.x, (N).w, (M).x, (M).y, (M).z, (M).w, (O).x, (O).y, (O).z)    \
    RUN(kr.y, ki.y, (N).z, (N).w, (M).x, (M).y, (M).z, (M).w, (O).x, (O).y)    \
    RUN(kr.z, ki.z, (N).y, (N).z, (N).w, (M).x, (M).y, (M).z, (M).w, (O).x)    \
    RUN(kr.w, ki.w, (N).x, (N).y, (N).z, (N).w, (M).x, (M).y, (M).z, (M).w)    \
}

// Direct conv for one rank: 8 contiguous outputs t = tstart + 8*tid + i.
// xs[p] = X[tstart + p - 53]; xbase = 2*tid + 25 (float4 index).
__device__ __forceinline__ void conv_rank(const float4* xs4,
                                          const float4* __restrict__ Kr,
                                          int xbase,
                                          float (&re)[8], float (&im)[8]) {
#pragma unroll
    for (int i = 0; i < 8; ++i) { re[i] = 0.f; im[i] = 0.f; }
    float4 A, B, C;
    B = xs4[xbase + 1];
    C = xs4[xbase + 2];
    CSTEP(0, A, B, C)  CSTEP(1, C, A, B)  CSTEP(2, B, C, A)
    CSTEP(3, A, B, C)  CSTEP(4, C, A, B)  CSTEP(5, B, C, A)
    CSTEP(6, A, B, C)  CSTEP(7, C, A, B)  CSTEP(8, B, C, A)
    CSTEP(9, A, B, C)  CSTEP(10, C, A, B) CSTEP(11, B, C, A)
    CSTEP(12, A, B, C) CSTEP(13, C, A, B) CSTEP(14, B, C, A)
    CSTEP(15, A, B, C) CSTEP(16, C, A, B) CSTEP(17, B, C, A)
    CSTEP(18, A, B, C) CSTEP(19, C, A, B) CSTEP(20, B, C, A)
    CSTEP(21, A, B, C) CSTEP(22, C, A, B) CSTEP(23, B, C, A)
    CSTEP(24, A, B, C)
    // epilogue: j = 100 (single tap). Window blocks {2tid+0, 2tid+1, 2tid+2}
    // = {new read, A, B}; uses w[3..10].
    C = xs4[xbase - 25];
    float krE = Kr[50].x;
    float kiE = Kr[51].x;
    RUN(krE, kiE, C.w, A.x, A.y, A.z, A.w, B.x, B.y, B.z)
}

// ---------------------------------------------------------------------------
// Repack K (rank,2,101) -> Kpi: per rank 26 slots of {re[4j4..+3], im[4j4..+3]}.
__global__ void k_prep(const float* __restrict__ K, float* __restrict__ Kpi) {
    int idx = blockIdx.x * 256 + threadIdx.x;
    if (idx >= RANK * KROW) return;
    int k = idx / KROW, r = idx % KROW;
    int slot = r >> 3, h = r & 7;
    int comp = h >> 2, jo = h & 3;
    int j = slot * 4 + jo;
    Kpi[idx] = (j < WLEN) ? K[(k * 2 + comp) * WLEN + j] : 0.f;
}

// ---------------------------------------------------------------------------
__device__ __forceinline__ void stage_x(const float* __restrict__ Xn,
                                        float* xs, int tstart) {
    for (int p = threadIdx.x; p < XSLEN; p += 256) {
        int g = tstart + p - 53;
        xs[p] = (g >= 0 && g < TLEN) ? Xn[g] : 0.f;
    }
}

// ---------------------------------------------------------------------------
// Pass 1: conv + |.|, optional c store, per-(n,k) sum/sumsq. grid (NT2, NIN).
template <int STORE_C>
__global__ void k_conv(const float* __restrict__ X,
                       const float* __restrict__ Kpi,
                       float* __restrict__ c,
                       float* __restrict__ sums,
                       float* __restrict__ sumsq) {
    __shared__ __align__(16) float xs[XSLEN];
    __shared__ float red1[4][RANK], red2[4][RANK];
    int n = blockIdx.y, tile = blockIdx.x, tid = threadIdx.x;
    int tstart = tile * TILE2;
    stage_x(X + (size_t)n * TLEN, xs, tstart);
    __syncthreads();

    const float4* xs4 = (const float4*)xs;
    int xbase = 2 * tid + 25;
    int tb = tstart + tid * 8;
    int wave = tid >> 6, lane = tid & 63;

#pragma unroll 1
    for (int k = 0; k < RANK; ++k) {
        const float4* Kr = (const float4*)(Kpi + k * KROW);
        float re[8], im[8];
        conv_rank(xs4, Kr, xbase, re, im);

        float4 cv0, cv1;
        float* cf = (float*)&cv0;
        float a = 0.f, b = 0.f;
#pragma unroll
        for (int i = 0; i < 8; ++i) {
            float v = sqrtf(fmaf(re[i], re[i], im[i] * im[i]));
            ((float*)&cv0)[0]; // no-op keep layout simple
            if (i < 4) ((float*)&cv0)[i] = v; else ((float*)&cv1)[i - 4] = v;
            float vm = (tb + i < TLEN) ? v : 0.f;
            a += vm;
            b = fmaf(vm, vm, b);
        }
        if (STORE_C && tb + 7 < TPADC) {
            float* dst = &c[((size_t)(n * RANK + k)) * TPADC + tb];
            *(float4*)dst = cv0;
            *(float4*)(dst + 4) = cv1;
        }
        for (int off = 32; off > 0; off >>= 1) {
            a += __shfl_down(a, off);
            b += __shfl_down(b, off);
        }
        if (lane == 0) { red1[wave][k] = a; red2[wave][k] = b; }
    }
    __syncthreads();
    if (tid < RANK) {
        float a = red1[0][tid] + red1[1][tid] + red1[2][tid] + red1[3][tid];
        atomicAdd(&sums[n * RANK + tid], a);
    } else if (tid >= 64 && tid < 64 + RANK) {
        int k = tid - 64;
        float b = red2[0][k] + red2[1][k] + red2[2][k] + red2[3][k];
        atomicAdd(&sumsq[n * RANK + k], b);
    }
}

// ---------------------------------------------------------------------------
// Finalize: W[n,k] = B1/std,  bias2[m] = bias[m] - sum mean*W*B2.
__global__ void k_fin(const float* __restrict__ sums,
                      const float* __restrict__ sumsq,
                      const float* __restrict__ B1,
                      const float* __restrict__ B2,
                      const float* __restrict__ bias,
                      float* __restrict__ Wm,
                      float* __restrict__ bias2) {
    __shared__ float mw[NIN * RANK];
    int tid = threadIdx.x;
    for (int idx = tid; idx < NIN * RANK; idx += 256) {
        float s = sums[idx], s2 = sumsq[idx];
        float mean = s / (float)TLEN;
        float var = fmaxf((s2 - s * mean) / (float)(TLEN - 1), 1e-12f);
        float w = B1[idx] / sqrtf(var);
        Wm[idx] = w;
        mw[idx] = mean * w;
    }
    __syncthreads();
    if (tid < NOUT) {
        float acc = bias[tid];
        for (int n = 0; n < NIN; ++n)
#pragma unroll
            for (int k = 0; k < RANK; ++k)
                acc -= mw[n * RANK + k] * B2[k * NOUT + tid];
        bias2[tid] = acc;
    }
}

// ---------------------------------------------------------------------------
// Pass 2 (BIG): read c, ypart[k,t] over an n-chunk. grid (TPADC/512, nch).
__global__ void k_comb(const float* __restrict__ c,
                       const float* __restrict__ Wm,
                       float* __restrict__ ypart, int npc) {
    int t2 = blockIdx.x * 256 + threadIdx.x;
    int ch = blockIdx.y;
    float2 y[RANK];
#pragma unroll
    for (int k = 0; k < RANK; ++k) y[k] = make_float2(0.f, 0.f);
    int n0 = ch * npc;
    for (int n = n0; n < n0 + npc; ++n) {
#pragma unroll
        for (int k = 0; k < RANK; ++k) {
            float2 cv = *(const float2*)&c[((size_t)(n * RANK + k)) * TPADC + 2 * t2];
            float w = Wm[n * RANK + k];
            y[k].x = fmaf(cv.x, w, y[k].x);
            y[k].y = fmaf(cv.y, w, y[k].y);
        }
    }
#pragma unroll
    for (int k = 0; k < RANK; ++k)
        *(float2*)&ypart[((size_t)(ch * RANK + k)) * TPADC + 2 * t2] = y[k];
}

// Pass 2 (SMALL): recompute conv, accumulate y over an n-chunk. grid (NT2, nch).
__global__ void k_comb_re(const float* __restrict__ X,
                          const float* __restrict__ Kpi,
                          const float* __restrict__ Wm,
                          float* __restrict__ ypart, int npc) {
    __shared__ __align__(16) float xs[XSLEN];
    int ch = blockIdx.y, tile = blockIdx.x, tid = threadIdx.x;
    int tstart = tile * TILE2;
    const float4* xs4 = (const float4*)xs;
    int xbase = 2 * tid + 25;
    float y[RANK][8];
#pragma unroll
    for (int k = 0; k < RANK; ++k)
#pragma unroll
        for (int i = 0; i < 8; ++i) y[k][i] = 0.f;

    int n0 = ch * npc;
#pragma unroll 1
    for (int n = n0; n < n0 + npc; ++n) {
        stage_x(X + (size_t)n * TLEN, xs, tstart);
        __syncthreads();
#pragma unroll 1
        for (int k = 0; k < RANK; ++k) {
            const float4* Kr = (const float4*)(Kpi + k * KROW);
            float re[8], im[8];
            conv_rank(xs4, Kr, xbase, re, im);
            float w = Wm[n * RANK + k];
#pragma unroll
            for (int i = 0; i < 8; ++i) {
                float v = sqrtf(fmaf(re[i], re[i], im[i] * im[i]));
                y[k][i] = fmaf(v, w, y[k][i]);
            }
        }
        __syncthreads();
    }
    int tb = tstart + tid * 8;
#pragma unroll
    for (int k = 0; k < RANK; ++k) {
        float* dst = &ypart[((size_t)(ch * RANK + k)) * TPAD2 + tb];
        *(float4*)dst = make_float4(y[k][0], y[k][1], y[k][2], y[k][3]);
        *(float4*)(dst + 4) = make_float4(y[k][4], y[k][5], y[k][6], y[k][7]);
    }
}

// ---------------------------------------------------------------------------
// Final: out[m,t] = bias2[m] + sum_k B2[k,m] * sum_ch ypart[ch,k,t].
__global__ void k_out(const float* __restrict__ ypart,
                      const float* __restrict__ B2,
                      const float* __restrict__ bias2,
                      float* __restrict__ out, int nch, int yrow) {
    int t2 = blockIdx.x * 256 + threadIdx.x;
    int t = 2 * t2;
    if (t >= TLEN) return;
    float2 y[RANK];
#pragma unroll
    for (int k = 0; k < RANK; ++k) y[k] = make_float2(0.f, 0.f);
    for (int ch = 0; ch < nch; ++ch) {
#pragma unroll
        for (int k = 0; k < RANK; ++k) {
            float2 v = *(const float2*)&ypart[((size_t)(ch * RANK + k)) * yrow + t];
            y[k].x += v.x;
            y[k].y += v.y;
        }
    }
    for (int m = 0; m < NOUT; ++m) {
        float b = bias2[m];
        float2 acc = make_float2(b, b);
#pragma unroll
        for (int k = 0; k < RANK; ++k) {
            float w = B2[k * NOUT + m];
            acc.x = fmaf(y[k].x, w, acc.x);
            acc.y = fmaf(y[k].y, w, acc.y);
        }
        *(float2*)&out[(size_t)m * TLEN + t] = acc;
    }
}

// ---------------------------------------------------------------------------
extern "C" void kernel_launch(void* const* d_in, const int* in_sizes, int n_in,
                              void* d_out, int out_size, void* d_ws, size_t ws_size,
                              hipStream_t stream) {
    const float* X    = (const float*)d_in[0];
    const float* K    = (const float*)d_in[1];
    const float* B1   = (const float*)d_in[2];
    const float* B2   = (const float*)d_in[3];
    const float* bias = (const float*)d_in[4];
    float* out = (float*)d_out;

    char* p = (char*)d_ws;
    size_t off = 0;
    auto alloc = [&](size_t bytes) -> void* {
        void* r = p + off;
        off += (bytes + 255) & ~(size_t)255;
        return r;
    };
    float* sums  = (float*)alloc(NIN * RANK * sizeof(float));
    float* sumsq = (float*)alloc(NIN * RANK * sizeof(float));
    float* Wm    = (float*)alloc(NIN * RANK * sizeof(float));
    float* bias2 = (float*)alloc(NOUT * sizeof(float));
    float* Kpi   = (float*)alloc(RANK * KROW * sizeof(float));

    size_t cbytes = (size_t)NIN * RANK * TPADC * sizeof(float);   // 256.9 MB
    auto ypb = [](int n, int row) {
        return (((size_t)n * RANK * row * sizeof(float)) + 255) & ~(size_t)255;
    };

    int mode, nch;
    if (ws_size >= off + ypb(8, TPADC) + cbytes)      { mode = 0; nch = 8; }
    else if (ws_size >= off + ypb(4, TPADC) + cbytes) { mode = 0; nch = 4; }
    else if (ws_size >= off + ypb(8, TPAD2))          { mode = 1; nch = 8; }
    else                                              { mode = 1; nch = 1; }

    int yrow = (mode == 0) ? TPADC : TPAD2;
    float* ypart = (float*)alloc((size_t)nch * RANK * yrow * sizeof(float));
    float* c     = (float*)(p + off);  // BIG path only

    hipMemsetAsync(sums, 0, 2 * NIN * RANK * sizeof(float), stream);

    k_prep<<<dim3((RANK * KROW + 255) / 256), 256, 0, stream>>>(K, Kpi);

    if (mode == 0)
        k_conv<1><<<dim3(NT2, NIN), 256, 0, stream>>>(X, Kpi, c, sums, sumsq);
    else
        k_conv<0><<<dim3(NT2, NIN), 256, 0, stream>>>(X, Kpi, c, sums, sumsq);

    k_fin<<<1, 256, 0, stream>>>(sums, sumsq, B1, B2, bias, Wm, bias2);

    if (mode == 0) {
        k_comb<<<dim3(TPADC / 512, nch), 256, 0, stream>>>(c, Wm, ypart, NIN / nch);
    } else {
        k_comb_re<<<dim3(NT2, nch), 256, 0, stream>>>(X, Kpi, Wm, ypart, NIN / nch);
    }

    k_out<<<dim3(TPADC / 512), 256, 0, stream>>>(ypart, B2, bias2, out, nch, yrow);
}

// Round 5
// 371.375 us; speedup vs baseline: 2.1890x; 2.1890x over previous
//
#include <hip/hip_runtime.h>
#include <hip/hip_bf16.h>

#define NIN   128
#define NOUT  64
#define RANK  10
#define WLEN  101
#define TLEN  50000
#define TILE  1024
#define NT    49
#define TPAD  (NT * TILE)   // 50176
#define NA    51            // j-pair steps: pairs (2a, 2a+1), k[101] = 0
#define XS2   1128          // packed entries; entry p <-> s = tstart - 55 + p

typedef _Float16 h2 __attribute__((ext_vector_type(2)));

__device__ __forceinline__ h2 as_h2(unsigned u) {
    union { unsigned x; h2 h; } c; c.x = u; return c.h;
}
__device__ __forceinline__ unsigned packh(float lo, float hi) {
    union { h2 h; unsigned u; } c;
    c.h.x = (_Float16)lo; c.h.y = (_Float16)hi; return c.u;
}

#if defined(__has_builtin)
#if __has_builtin(__builtin_amdgcn_fdot2)
#define FDOT2(a, b, c) __builtin_amdgcn_fdot2((a), (b), (c), false)
#endif
#endif
#ifndef FDOT2
__device__ __forceinline__ float fdot2_sw(h2 a, h2 b, float c) {
    return fmaf((float)a.x, (float)b.x, fmaf((float)a.y, (float)b.y, c));
}
#define FDOT2(a, b, c) fdot2_sw((a), (b), (c))
#endif

// ---------------------------------------------------------------------------
// Taps: Kd[k*NA + a] = { re_pair, im_pair }, pair = (lo=k[2a], hi=k[2a+1]),
// with k[101] = 0.
__global__ void k_prep(const float* __restrict__ K, uint2* __restrict__ Kd) {
    int idx = blockIdx.x * 256 + threadIdx.x;
    if (idx >= RANK * NA) return;
    int k = idx / NA, a = idx % NA;
    int j0 = 2 * a, j1 = 2 * a + 1;
    float r0 = K[(k * 2 + 0) * WLEN + j0];
    float i0 = K[(k * 2 + 1) * WLEN + j0];
    float r1 = (j1 < WLEN) ? K[(k * 2 + 0) * WLEN + j1] : 0.f;
    float i1 = (j1 < WLEN) ? K[(k * 2 + 1) * WLEN + j1] : 0.f;
    Kd[idx] = make_uint2(packh(r0, r1), packh(i0, i1));
}

// ---------------------------------------------------------------------------
// Stage packed reversed pairs: Rs[p] = (lo=x[s+1], hi=x[s]), s = tstart-55+p,
// zero-padded outside [0, TLEN).
__device__ __forceinline__ void stage_R(const float* __restrict__ Xn,
                                        unsigned* Rs, int tstart) {
    for (int p = threadIdx.x; p < XS2; p += 256) {
        int s = tstart - 55 + p;
        float x0 = (s >= 0 && s < TLEN) ? Xn[s] : 0.f;
        float x1 = (s + 1 >= 0 && s + 1 < TLEN) ? Xn[s + 1] : 0.f;
        Rs[p] = packh(x1, x0);
    }
}

// Core: all 10 ranks, 4 consecutive t = tstart + 4*tid + i.
// Per step a: x[t+50-2a]*k[2a] + x[t+49-2a]*k[2a+1] = fdot2(Rs[t+49-2a], pair).
__device__ __forceinline__ void conv_all(const unsigned* Rs,
                                         const uint2* __restrict__ Kd,
                                         int tid,
                                         float (&re)[RANK][4],
                                         float (&im)[RANK][4]) {
#pragma unroll
    for (int k = 0; k < RANK; ++k)
#pragma unroll
        for (int i = 0; i < 4; ++i) { re[k][i] = 0.f; im[k][i] = 0.f; }

    int pb = 4 * tid + 104;
    for (int a = 0; a < NA; ++a) {
        int p = pb - 2 * a;                       // even -> 8B aligned
        uint2 wa = *(const uint2*)&Rs[p];
        uint2 wb = *(const uint2*)&Rs[p + 2];
        h2 w0 = as_h2(wa.x), w1 = as_h2(wa.y);
        h2 w2 = as_h2(wb.x), w3 = as_h2(wb.y);
#pragma unroll
        for (int k = 0; k < RANK; ++k) {
            uint2 kp = Kd[k * NA + a];            // wave-uniform
            h2 br = as_h2(kp.x), bi = as_h2(kp.y);
            re[k][0] = FDOT2(w0, br, re[k][0]); im[k][0] = FDOT2(w0, bi, im[k][0]);
            re[k][1] = FDOT2(w1, br, re[k][1]); im[k][1] = FDOT2(w1, bi, im[k][1]);
            re[k][2] = FDOT2(w2, br, re[k][2]); im[k][2] = FDOT2(w2, bi, im[k][2]);
            re[k][3] = FDOT2(w3, br, re[k][3]); im[k][3] = FDOT2(w3, bi, im[k][3]);
        }
    }
}

// ---------------------------------------------------------------------------
// Pass 1: conv + |.|, optional c store, per-(n,k) sum/sumsq. grid (NT, NIN).
template <int STORE_C>
__global__ __launch_bounds__(256, 4) void k_conv(const float* __restrict__ X,
                       const uint2* __restrict__ Kd,
                       float* __restrict__ c,
                       float* __restrict__ sums,
                       float* __restrict__ sumsq) {
    __shared__ __align__(16) unsigned Rs[XS2];
    __shared__ float red1[4][RANK], red2[4][RANK];
    int n = blockIdx.y, tile = blockIdx.x, tid = threadIdx.x;
    int tstart = tile * TILE;
    stage_R(X + (size_t)n * TLEN, Rs, tstart);
    __syncthreads();

    float re[RANK][4], im[RANK][4];
    conv_all(Rs, Kd, tid, re, im);

    int tb = tstart + tid * 4;
    int wave = tid >> 6, lane = tid & 63;
#pragma unroll
    for (int k = 0; k < RANK; ++k) {
        float4 cv;
        float a = 0.f, b = 0.f;
#pragma unroll
        for (int i = 0; i < 4; ++i) {
            float v = sqrtf(fmaf(re[k][i], re[k][i], im[k][i] * im[k][i]));
            ((float*)&cv)[i] = v;
            float vm = (tb + i < TLEN) ? v : 0.f;  // exact stats
            a += vm;
            b = fmaf(vm, vm, b);
        }
        if (STORE_C) {
            *(float4*)&c[((size_t)(n * RANK + k)) * TPAD + tb] = cv;
        }
        for (int off = 32; off > 0; off >>= 1) {
            a += __shfl_down(a, off);
            b += __shfl_down(b, off);
        }
        if (lane == 0) { red1[wave][k] = a; red2[wave][k] = b; }
    }
    __syncthreads();
    if (tid < RANK) {
        float a = red1[0][tid] + red1[1][tid] + red1[2][tid] + red1[3][tid];
        atomicAdd(&sums[n * RANK + tid], a);
    } else if (tid >= 64 && tid < 64 + RANK) {
        int k = tid - 64;
        float b = red2[0][k] + red2[1][k] + red2[2][k] + red2[3][k];
        atomicAdd(&sumsq[n * RANK + k], b);
    }
}

// ---------------------------------------------------------------------------
// Finalize: W[n,k] = B1/std,  bias2[m] = bias[m] - sum mean*W*B2.
__global__ void k_fin(const float* __restrict__ sums,
                      const float* __restrict__ sumsq,
                      const float* __restrict__ B1,
                      const float* __restrict__ B2,
                      const float* __restrict__ bias,
                      float* __restrict__ Wm,
                      float* __restrict__ bias2) {
    __shared__ float mw[NIN * RANK];
    int tid = threadIdx.x;
    for (int idx = tid; idx < NIN * RANK; idx += 256) {
        float s = sums[idx], s2 = sumsq[idx];
        float mean = s / (float)TLEN;
        float var = fmaxf((s2 - s * mean) / (float)(TLEN - 1), 1e-12f);
        float w = B1[idx] / sqrtf(var);
        Wm[idx] = w;
        mw[idx] = mean * w;
    }
    __syncthreads();
    if (tid < NOUT) {
        float acc = bias[tid];
        for (int n = 0; n < NIN; ++n)
#pragma unroll
            for (int k = 0; k < RANK; ++k)
                acc -= mw[n * RANK + k] * B2[k * NOUT + tid];
        bias2[tid] = acc;
    }
}

// ---------------------------------------------------------------------------
// Pass 2 (BIG): read c, ypart[ch,k,t] over an n-chunk. grid (TPAD/512, nch).
__global__ void k_comb(const float* __restrict__ c,
                       const float* __restrict__ Wm,
                       float* __restrict__ ypart, int npc) {
    int t2 = blockIdx.x * 256 + threadIdx.x;
    int ch = blockIdx.y;
    float2 y[RANK];
#pragma unroll
    for (int k = 0; k < RANK; ++k) y[k] = make_float2(0.f, 0.f);
    int n0 = ch * npc;
    for (int n = n0; n < n0 + npc; ++n) {
#pragma unroll
        for (int k = 0; k < RANK; ++k) {
            float2 cv = *(const float2*)&c[((size_t)(n * RANK + k)) * TPAD + 2 * t2];
            float w = Wm[n * RANK + k];
            y[k].x = fmaf(cv.x, w, y[k].x);
            y[k].y = fmaf(cv.y, w, y[k].y);
        }
    }
#pragma unroll
    for (int k = 0; k < RANK; ++k)
        *(float2*)&ypart[((size_t)(ch * RANK + k)) * TPAD + 2 * t2] = y[k];
}

// Pass 2 (SMALL): recompute conv, accumulate y over an n-chunk. grid (NT, nch).
__global__ __launch_bounds__(256, 4) void k_comb_re(const float* __restrict__ X,
                          const uint2* __restrict__ Kd,
                          const float* __restrict__ Wm,
                          float* __restrict__ ypart, int npc) {
    __shared__ __align__(16) unsigned Rs[XS2];
    int ch = blockIdx.y, tile = blockIdx.x, tid = threadIdx.x;
    int tstart = tile * TILE;
    float y[RANK][4];
#pragma unroll
    for (int k = 0; k < RANK; ++k)
#pragma unroll
        for (int i = 0; i < 4; ++i) y[k][i] = 0.f;

    int n0 = ch * npc;
#pragma unroll 1
    for (int n = n0; n < n0 + npc; ++n) {
        stage_R(X + (size_t)n * TLEN, Rs, tstart);
        __syncthreads();
        float re[RANK][4], im[RANK][4];
        conv_all(Rs, Kd, tid, re, im);
#pragma unroll
        for (int k = 0; k < RANK; ++k) {
            float w = Wm[n * RANK + k];
#pragma unroll
            for (int i = 0; i < 4; ++i) {
                float v = sqrtf(fmaf(re[k][i], re[k][i], im[k][i] * im[k][i]));
                y[k][i] = fmaf(v, w, y[k][i]);
            }
        }
        __syncthreads();
    }
    int tb = tstart + tid * 4;
#pragma unroll
    for (int k = 0; k < RANK; ++k) {
        *(float4*)&ypart[((size_t)(ch * RANK + k)) * TPAD + tb] =
            make_float4(y[k][0], y[k][1], y[k][2], y[k][3]);
    }
}

// ---------------------------------------------------------------------------
// Final: out[m,t] = bias2[m] + sum_k B2[k,m] * sum_ch ypart[ch,k,t].
__global__ void k_out(const float* __restrict__ ypart,
                      const float* __restrict__ B2,
                      const float* __restrict__ bias2,
                      float* __restrict__ out, int nch) {
    int t2 = blockIdx.x * 256 + threadIdx.x;
    int t = 2 * t2;
    if (t >= TLEN) return;
    float2 y[RANK];
#pragma unroll
    for (int k = 0; k < RANK; ++k) y[k] = make_float2(0.f, 0.f);
    for (int ch = 0; ch < nch; ++ch) {
#pragma unroll
        for (int k = 0; k < RANK; ++k) {
            float2 v = *(const float2*)&ypart[((size_t)(ch * RANK + k)) * TPAD + t];
            y[k].x += v.x;
            y[k].y += v.y;
        }
    }
    for (int m = 0; m < NOUT; ++m) {
        float b = bias2[m];
        float2 acc = make_float2(b, b);
#pragma unroll
        for (int k = 0; k < RANK; ++k) {
            float w = B2[k * NOUT + m];
            acc.x = fmaf(y[k].x, w, acc.x);
            acc.y = fmaf(y[k].y, w, acc.y);
        }
        *(float2*)&out[(size_t)m * TLEN + t] = acc;
    }
}

// ---------------------------------------------------------------------------
extern "C" void kernel_launch(void* const* d_in, const int* in_sizes, int n_in,
                              void* d_out, int out_size, void* d_ws, size_t ws_size,
                              hipStream_t stream) {
    const float* X    = (const float*)d_in[0];
    const float* K    = (const float*)d_in[1];
    const float* B1   = (const float*)d_in[2];
    const float* B2   = (const float*)d_in[3];
    const float* bias = (const float*)d_in[4];
    float* out = (float*)d_out;

    char* p = (char*)d_ws;
    size_t off = 0;
    auto alloc = [&](size_t bytes) -> void* {
        void* r = p + off;
        off += (bytes + 255) & ~(size_t)255;
        return r;
    };
    float* sums  = (float*)alloc(NIN * RANK * sizeof(float));
    float* sumsq = (float*)alloc(NIN * RANK * sizeof(float));
    float* Wm    = (float*)alloc(NIN * RANK * sizeof(float));
    float* bias2 = (float*)alloc(NOUT * sizeof(float));
    uint2* Kd    = (uint2*)alloc(RANK * NA * sizeof(uint2));

    size_t cbytes = (size_t)NIN * RANK * TPAD * sizeof(float);   // 256.9 MB
    auto ypb = [](int n) {
        return (((size_t)n * RANK * TPAD * sizeof(float)) + 255) & ~(size_t)255;
    };

    int mode, nch;
    if (ws_size >= off + ypb(8) + cbytes)      { mode = 0; nch = 8; }
    else if (ws_size >= off + ypb(4) + cbytes) { mode = 0; nch = 4; }
    else if (ws_size >= off + ypb(8))          { mode = 1; nch = 8; }
    else                                       { mode = 1; nch = 1; }

    float* ypart = (float*)alloc((size_t)nch * RANK * TPAD * sizeof(float));
    float* c     = (float*)(p + off);  // BIG path only

    hipMemsetAsync(sums, 0, 2 * NIN * RANK * sizeof(float), stream);

    k_prep<<<dim3((RANK * NA + 255) / 256), 256, 0, stream>>>(K, Kd);

    if (mode == 0)
        k_conv<1><<<dim3(NT, NIN), 256, 0, stream>>>(X, Kd, c, sums, sumsq);
    else
        k_conv<0><<<dim3(NT, NIN), 256, 0, stream>>>(X, Kd, c, sums, sumsq);

    k_fin<<<1, 256, 0, stream>>>(sums, sumsq, B1, B2, bias, Wm, bias2);

    if (mode == 0) {
        k_comb<<<dim3(TPAD / 512, nch), 256, 0, stream>>>(c, Wm, ypart, NIN / nch);
    } else {
        k_comb_re<<<dim3(NT, nch), 256, 0, stream>>>(X, Kd, Wm, ypart, NIN / nch);
    }

    k_out<<<dim3(TPAD / 512), 256, 0, stream>>>(ypart, B2, bias2, out, nch);
}

// Round 7
// 364.765 us; speedup vs baseline: 2.2286x; 1.0181x over previous
//
#include <hip/hip_runtime.h>
#include <hip/hip_bf16.h>

#define NIN   128
#define NOUT  64
#define RANK  10
#define WLEN  101
#define TLEN  50000
#define TILE  512
#define NTT   98
#define TPAD  (NTT * TILE)   // 50176
#define NA    51             // tap-pair steps; k[101] = 0
#define XS    616            // Rs entries; Rs[p] <-> s = tstart - 55 + p
#define KLDS  (NA * 20)      // 1020 dwords of packed taps

typedef _Float16 h2 __attribute__((ext_vector_type(2)));

__device__ __forceinline__ h2 as_h2(unsigned u) {
    union { unsigned x; h2 h; } c; c.x = u; return c.h;
}
__device__ __forceinline__ unsigned packh(float lo, float hi) {
    union { h2 h; unsigned u; } c;
    c.h.x = (_Float16)lo; c.h.y = (_Float16)hi; return c.u;
}

#if defined(__has_builtin)
#if __has_builtin(__builtin_amdgcn_fdot2)
#define FDOT2(a, b, c) __builtin_amdgcn_fdot2((a), (b), (c), false)
#endif
#endif
#ifndef FDOT2
__device__ __forceinline__ float fdot2_sw(h2 a, h2 b, float c) {
    return fmaf((float)a.x, (float)b.x, fmaf((float)a.y, (float)b.y, c));
}
#define FDOT2(a, b, c) fdot2_sw((a), (b), (c))
#endif

// ---------------------------------------------------------------------------
// Taps packed [a][k][comp]: Kd2[a*20 + 2k + comp] = packh(k[2a], k[2a+1]).
__global__ void k_prep(const float* __restrict__ K, unsigned* __restrict__ Kd2) {
    int idx = blockIdx.x * 256 + threadIdx.x;
    if (idx >= KLDS) return;
    int a = idx / 20, r = idx % 20;
    int k = r >> 1, comp = r & 1;
    int j0 = 2 * a, j1 = 2 * a + 1;
    float v0 = K[(k * 2 + comp) * WLEN + j0];
    float v1 = (j1 < WLEN) ? K[(k * 2 + comp) * WLEN + j1] : 0.f;
    Kd2[idx] = packh(v0, v1);
}

// ---------------------------------------------------------------------------
// Rs[p] = packh(x[s+1], x[s]), s = tstart - 55 + p, zero-padded.
__device__ __forceinline__ void stage_R(const float* __restrict__ Xn,
                                        unsigned* Rs, int tstart) {
    for (int p = threadIdx.x; p < XS; p += 256) {
        int s = tstart - 55 + p;
        float x0 = (s >= 0 && s < TLEN) ? Xn[s] : 0.f;
        float x1 = (s + 1 >= 0 && s + 1 < TLEN) ? Xn[s + 1] : 0.f;
        Rs[p] = packh(x1, x0);
    }
}

// Core: all 10 ranks, 2 consecutive t = tstart + 2*tid + i.
// Step a contributes fdot2(Rs[pb - 2a + i], tap_pair_a).
__device__ __forceinline__ void conv_all(const unsigned* Rs, const unsigned* Kl,
                                         int tid,
                                         float (&re)[RANK][2],
                                         float (&im)[RANK][2]) {
#pragma unroll
    for (int k = 0; k < RANK; ++k) {
        re[k][0] = 0.f; re[k][1] = 0.f; im[k][0] = 0.f; im[k][1] = 0.f;
    }
    int pb = 2 * tid + 104;
#pragma unroll 1
    for (int ap = 0; ap < 25; ++ap) {
        int p = pb - 4 * ap;
        uint2 wA = *(const uint2*)&Rs[p];       // step 2ap   (i = 0,1)
        uint2 wB = *(const uint2*)&Rs[p - 2];   // step 2ap+1
        h2 e0 = as_h2(wA.x), e1 = as_h2(wA.y);
        h2 o0 = as_h2(wB.x), o1 = as_h2(wB.y);
        const uint4* t0 = (const uint4*)&Kl[40 * ap];        // uniform
        const uint4* t1 = (const uint4*)&Kl[40 * ap + 20];
#pragma unroll
        for (int kp = 0; kp < 5; ++kp) {
            const int k0 = 2 * kp, k1 = 2 * kp + 1;
            uint4 ta = t0[kp];
            h2 r0 = as_h2(ta.x), i0 = as_h2(ta.y);
            h2 r1 = as_h2(ta.z), i1 = as_h2(ta.w);
            re[k0][0] = FDOT2(e0, r0, re[k0][0]); im[k0][0] = FDOT2(e0, i0, im[k0][0]);
            re[k0][1] = FDOT2(e1, r0, re[k0][1]); im[k0][1] = FDOT2(e1, i0, im[k0][1]);
            re[k1][0] = FDOT2(e0, r1, re[k1][0]); im[k1][0] = FDOT2(e0, i1, im[k1][0]);
            re[k1][1] = FDOT2(e1, r1, re[k1][1]); im[k1][1] = FDOT2(e1, i1, im[k1][1]);
            uint4 tb = t1[kp];
            h2 s0 = as_h2(tb.x), j0 = as_h2(tb.y);
            h2 s1 = as_h2(tb.z), j1 = as_h2(tb.w);
            re[k0][0] = FDOT2(o0, s0, re[k0][0]); im[k0][0] = FDOT2(o0, j0, im[k0][0]);
            re[k0][1] = FDOT2(o1, s0, re[k0][1]); im[k0][1] = FDOT2(o1, j0, im[k0][1]);
            re[k1][0] = FDOT2(o0, s1, re[k1][0]); im[k1][0] = FDOT2(o0, j1, im[k1][0]);
            re[k1][1] = FDOT2(o1, s1, re[k1][1]); im[k1][1] = FDOT2(o1, j1, im[k1][1]);
        }
    }
    // tail step a = 50
    {
        int p = pb - 100;
        uint2 wA = *(const uint2*)&Rs[p];
        h2 e0 = as_h2(wA.x), e1 = as_h2(wA.y);
        const uint4* t0 = (const uint4*)&Kl[1000];
#pragma unroll
        for (int kp = 0; kp < 5; ++kp) {
            const int k0 = 2 * kp, k1 = 2 * kp + 1;
            uint4 ta = t0[kp];
            h2 r0 = as_h2(ta.x), i0 = as_h2(ta.y);
            h2 r1 = as_h2(ta.z), i1 = as_h2(ta.w);
            re[k0][0] = FDOT2(e0, r0, re[k0][0]); im[k0][0] = FDOT2(e0, i0, im[k0][0]);
            re[k0][1] = FDOT2(e1, r0, re[k0][1]); im[k0][1] = FDOT2(e1, i0, im[k0][1]);
            re[k1][0] = FDOT2(e0, r1, re[k1][0]); im[k1][0] = FDOT2(e0, i1, im[k1][0]);
            re[k1][1] = FDOT2(e1, r1, re[k1][1]); im[k1][1] = FDOT2(e1, i1, im[k1][1]);
        }
    }
}

// ---------------------------------------------------------------------------
// Pass 1: conv + |.|, c stored as f16 pairs, per-(n,k) sum/sumsq. grid (NTT,NIN).
template <int STORE_C>
__global__ __launch_bounds__(256, 4) void k_conv(const float* __restrict__ X,
                       const unsigned* __restrict__ Kd2,
                       unsigned* __restrict__ ch,
                       float* __restrict__ sums,
                       float* __restrict__ sumsq) {
    __shared__ __align__(16) unsigned Rs[XS];
    __shared__ __align__(16) unsigned Kl[KLDS];
    __shared__ float red1[4][RANK], red2[4][RANK];
    int n = blockIdx.y, tile = blockIdx.x, tid = threadIdx.x;
    int tstart = tile * TILE;
    for (int idx = tid; idx < KLDS; idx += 256) Kl[idx] = Kd2[idx];
    stage_R(X + (size_t)n * TLEN, Rs, tstart);
    __syncthreads();

    float re[RANK][2], im[RANK][2];
    conv_all(Rs, Kl, tid, re, im);

    int tb = tstart + 2 * tid;
    int wave = tid >> 6, lane = tid & 63;
#pragma unroll
    for (int k = 0; k < RANK; ++k) {
        float v0 = sqrtf(fmaf(re[k][0], re[k][0], im[k][0] * im[k][0]));
        float v1 = sqrtf(fmaf(re[k][1], re[k][1], im[k][1] * im[k][1]));
        if (STORE_C)
            ch[((size_t)(n * RANK + k)) * (TPAD >> 1) + tile * 256 + tid] = packh(v0, v1);
        float m0 = (tb < TLEN) ? v0 : 0.f;
        float m1 = (tb + 1 < TLEN) ? v1 : 0.f;
        float a = m0 + m1;
        float b = fmaf(m0, m0, m1 * m1);
        for (int off = 32; off > 0; off >>= 1) {
            a += __shfl_down(a, off);
            b += __shfl_down(b, off);
        }
        if (lane == 0) { red1[wave][k] = a; red2[wave][k] = b; }
    }
    __syncthreads();
    if (tid < RANK) {
        float a = red1[0][tid] + red1[1][tid] + red1[2][tid] + red1[3][tid];
        atomicAdd(&sums[n * RANK + tid], a);
    } else if (tid >= 64 && tid < 64 + RANK) {
        int k = tid - 64;
        float b = red2[0][k] + red2[1][k] + red2[2][k] + red2[3][k];
        atomicAdd(&sumsq[n * RANK + k], b);
    }
}

// ---------------------------------------------------------------------------
// Finalize: W[n,k] = B1/std,  bias2[m] = bias[m] - sum mean*W*B2.
__global__ void k_fin(const float* __restrict__ sums,
                      const float* __restrict__ sumsq,
                      const float* __restrict__ B1,
                      const float* __restrict__ B2,
                      const float* __restrict__ bias,
                      float* __restrict__ Wm,
                      float* __restrict__ bias2) {
    __shared__ float mw[NIN * RANK];
    int tid = threadIdx.x;
    for (int idx = tid; idx < NIN * RANK; idx += 256) {
        float s = sums[idx], s2 = sumsq[idx];
        float mean = s / (float)TLEN;
        float var = fmaxf((s2 - s * mean) / (float)(TLEN - 1), 1e-12f);
        float w = B1[idx] / sqrtf(var);
        Wm[idx] = w;
        mw[idx] = mean * w;
    }
    __syncthreads();
    if (tid < NOUT) {
        float acc = bias[tid];
        for (int n = 0; n < NIN; ++n)
#pragma unroll
            for (int k = 0; k < RANK; ++k)
                acc -= mw[n * RANK + k] * B2[k * NOUT + tid];
        bias2[tid] = acc;
    }
}

// ---------------------------------------------------------------------------
// Pass 2 (BIG): read f16 c, ypart[ch,k,t] over an n-chunk. grid (NTT, nch).
__global__ void k_comb(const unsigned* __restrict__ ch,
                       const float* __restrict__ Wm,
                       float* __restrict__ ypart, int npc) {
    __shared__ float wl[NIN * RANK / 4];   // up to npc*RANK, npc<=32
    int t2 = blockIdx.x * 256 + threadIdx.x;   // dword idx: t = 2*t2, 2*t2+1
    int chn = blockIdx.y, tid = threadIdx.x;
    int n0 = chn * npc;
    for (int idx = tid; idx < npc * RANK; idx += 256)
        wl[idx] = Wm[n0 * RANK + idx];
    __syncthreads();
    float2 y[RANK];
#pragma unroll
    for (int k = 0; k < RANK; ++k) y[k] = make_float2(0.f, 0.f);
    for (int nn = 0; nn < npc; ++nn) {
#pragma unroll
        for (int k = 0; k < RANK; ++k) {
            unsigned u = ch[((size_t)((n0 + nn) * RANK + k)) * (TPAD >> 1) + t2];
            h2 v = as_h2(u);
            float w = wl[nn * RANK + k];
            y[k].x = fmaf((float)v.x, w, y[k].x);
            y[k].y = fmaf((float)v.y, w, y[k].y);
        }
    }
#pragma unroll
    for (int k = 0; k < RANK; ++k)
        *(float2*)&ypart[((size_t)(chn * RANK + k)) * TPAD + 2 * t2] = y[k];
}

// Pass 2 (SMALL fallback): recompute conv, accumulate over n-chunk. grid (NTT, nch).
__global__ __launch_bounds__(256, 4) void k_comb_re(const float* __restrict__ X,
                          const unsigned* __restrict__ Kd2,
                          const float* __restrict__ Wm,
                          float* __restrict__ ypart, int npc) {
    __shared__ __align__(16) unsigned Rs[XS];
    __shared__ __align__(16) unsigned Kl[KLDS];
    int chn = blockIdx.y, tile = blockIdx.x, tid = threadIdx.x;
    int tstart = tile * TILE;
    for (int idx = tid; idx < KLDS; idx += 256) Kl[idx] = Kd2[idx];
    float y[RANK][2];
#pragma unroll
    for (int k = 0; k < RANK; ++k) { y[k][0] = 0.f; y[k][1] = 0.f; }
    int n0 = chn * npc;
#pragma unroll 1
    for (int nn = 0; nn < npc; ++nn) {
        int n = n0 + nn;
        stage_R(X + (size_t)n * TLEN, Rs, tstart);
        __syncthreads();
        float re[RANK][2], im[RANK][2];
        conv_all(Rs, Kl, tid, re, im);
#pragma unroll
        for (int k = 0; k < RANK; ++k) {
            float w = Wm[n * RANK + k];
            float v0 = sqrtf(fmaf(re[k][0], re[k][0], im[k][0] * im[k][0]));
            float v1 = sqrtf(fmaf(re[k][1], re[k][1], im[k][1] * im[k][1]));
            y[k][0] = fmaf(v0, w, y[k][0]);
            y[k][1] = fmaf(v1, w, y[k][1]);
        }
        __syncthreads();
    }
    int tb = tstart + 2 * tid;
#pragma unroll
    for (int k = 0; k < RANK; ++k)
        *(float2*)&ypart[((size_t)(chn * RANK + k)) * TPAD + tb] =
            make_float2(y[k][0], y[k][1]);
}

// ---------------------------------------------------------------------------
// Final: out[m,t] = bias2[m] + sum_k B2[k,m] * sum_ch ypart[ch,k,t].
__global__ void k_out(const float* __restrict__ ypart,
                      const float* __restrict__ B2,
                      const float* __restrict__ bias2,
                      float* __restrict__ out, int nch) {
    int t2 = blockIdx.x * 256 + threadIdx.x;
    int t = 2 * t2;
    if (t >= TLEN) return;
    float2 y[RANK];
#pragma unroll
    for (int k = 0; k < RANK; ++k) y[k] = make_float2(0.f, 0.f);
    for (int chn = 0; chn < nch; ++chn) {
#pragma unroll
        for (int k = 0; k < RANK; ++k) {
            float2 v = *(const float2*)&ypart[((size_t)(chn * RANK + k)) * TPAD + t];
            y[k].x += v.x;
            y[k].y += v.y;
        }
    }
    for (int m = 0; m < NOUT; ++m) {
        float b = bias2[m];
        float2 acc = make_float2(b, b);
#pragma unroll
        for (int k = 0; k < RANK; ++k) {
            float w = B2[k * NOUT + m];
            acc.x = fmaf(y[k].x, w, acc.x);
            acc.y = fmaf(y[k].y, w, acc.y);
        }
        *(float2*)&out[(size_t)m * TLEN + t] = acc;
    }
}

// ---------------------------------------------------------------------------
extern "C" void kernel_launch(void* const* d_in, const int* in_sizes, int n_in,
                              void* d_out, int out_size, void* d_ws, size_t ws_size,
                              hipStream_t stream) {
    const float* X    = (const float*)d_in[0];
    const float* K    = (const float*)d_in[1];
    const float* B1   = (const float*)d_in[2];
    const float* B2   = (const float*)d_in[3];
    const float* bias = (const float*)d_in[4];
    float* out = (float*)d_out;

    char* p = (char*)d_ws;
    size_t off = 0;
    auto alloc = [&](size_t bytes) -> void* {
        void* r = p + off;
        off += (bytes + 255) & ~(size_t)255;
        return r;
    };
    float* sums  = (float*)alloc(NIN * RANK * sizeof(float));
    float* sumsq = (float*)alloc(NIN * RANK * sizeof(float));
    float* Wm    = (float*)alloc(NIN * RANK * sizeof(float));
    float* bias2 = (float*)alloc(NOUT * sizeof(float));
    unsigned* Kd2 = (unsigned*)alloc(KLDS * sizeof(unsigned));

    size_t cbytes = (size_t)NIN * RANK * (TPAD >> 1) * sizeof(unsigned); // 128.5 MB
    auto ypb = [](int n) {
        return (((size_t)n * RANK * TPAD * sizeof(float)) + 255) & ~(size_t)255;
    };

    int mode, nch;
    if (ws_size >= off + ypb(8) + cbytes)      { mode = 0; nch = 8; }
    else if (ws_size >= off + ypb(4) + cbytes) { mode = 0; nch = 4; }
    else if (ws_size >= off + ypb(8))          { mode = 1; nch = 8; }
    else                                       { mode = 1; nch = 1; }

    float* ypart = (float*)alloc((size_t)nch * RANK * TPAD * sizeof(float));
    unsigned* c  = (unsigned*)(p + off);  // BIG path only

    hipMemsetAsync(sums, 0, 2 * NIN * RANK * sizeof(float), stream);

    k_prep<<<dim3((KLDS + 255) / 256), 256, 0, stream>>>(K, Kd2);

    if (mode == 0)
        k_conv<1><<<dim3(NTT, NIN), 256, 0, stream>>>(X, Kd2, c, sums, sumsq);
    else
        k_conv<0><<<dim3(NTT, NIN), 256, 0, stream>>>(X, Kd2, c, sums, sumsq);

    k_fin<<<1, 256, 0, stream>>>(sums, sumsq, B1, B2, bias, Wm, bias2);

    if (mode == 0) {
        k_comb<<<dim3(NTT, nch), 256, 0, stream>>>(c, Wm, ypart, NIN / nch);
    } else {
        k_comb_re<<<dim3(NTT, nch), 256, 0, stream>>>(X, Kd2, Wm, ypart, NIN / nch);
    }

    k_out<<<dim3(TPAD / 512), 256, 0, stream>>>(ypart, B2, bias2, out, nch);
}

// Round 8
// 223.460 us; speedup vs baseline: 3.6379x; 1.6324x over previous
//
#include <hip/hip_runtime.h>
#include <hip/hip_bf16.h>

#define NIN   128
#define NOUT  64
#define RANK  10
#define WLEN  101
#define TLEN  50000
#define TILE  512
#define NTT   98
#define TPAD  (NTT * TILE)   // 50176
#define NA    51             // tap-pair steps (fallback path); k[101] = 0
#define XS    616            // fallback Rs entries
#define KLDS  (NA * 20)      // fallback packed taps (dwords)
#define RLEN  648            // reversed-X f16 entries per block (MFMA path)
#define CBOFF 561            // Cbase = t0 + 561

typedef _Float16 h2 __attribute__((ext_vector_type(2)));
typedef _Float16 half8 __attribute__((ext_vector_type(8)));
typedef float f32x4 __attribute__((ext_vector_type(4)));

__device__ __forceinline__ h2 as_h2(unsigned u) {
    union { unsigned x; h2 h; } c; c.x = u; return c.h;
}
__device__ __forceinline__ unsigned packh(float lo, float hi) {
    union { h2 h; unsigned u; } c;
    c.h.x = (_Float16)lo; c.h.y = (_Float16)hi; return c.u;
}
__device__ __forceinline__ unsigned short h16(float v) {
    union { _Float16 h; unsigned short u; } c;
    c.h = (_Float16)v; return c.u;
}

#if defined(__has_builtin)
#if __has_builtin(__builtin_amdgcn_fdot2)
#define FDOT2(a, b, c) __builtin_amdgcn_fdot2((a), (b), (c), false)
#endif
#endif
#ifndef FDOT2
__device__ __forceinline__ float fdot2_sw(h2 a, h2 b, float c) {
    return fmaf((float)a.x, (float)b.x, fmaf((float)a.y, (float)b.y, c));
}
#define FDOT2(a, b, c) fdot2_sw((a), (b), (c))
#endif

// ---------------------------------------------------------------------------
// Tap matrix for MFMA: Af[32][128] f16, row = 2*rank + comp, zero-padded.
__global__ void k_prep_taps(const float* __restrict__ K, _Float16* __restrict__ Af) {
    int idx = blockIdx.x * 256 + threadIdx.x;
    if (idx >= 32 * 128) return;
    int row = idx >> 7, j = idx & 127;
    int rank = row >> 1, comp = row & 1;
    float v = (rank < RANK && j < WLEN) ? K[(rank * 2 + comp) * WLEN + j] : 0.f;
    Af[idx] = (_Float16)v;
}

// Fallback-path taps: Kd2[a*20 + 2k + comp] = packh(k[2a], k[2a+1]).
__global__ void k_prep(const float* __restrict__ K, unsigned* __restrict__ Kd2) {
    int idx = blockIdx.x * 256 + threadIdx.x;
    if (idx >= KLDS) return;
    int a = idx / 20, r = idx % 20;
    int k = r >> 1, comp = r & 1;
    int j0 = 2 * a, j1 = 2 * a + 1;
    float v0 = K[(k * 2 + comp) * WLEN + j0];
    float v1 = (j1 < WLEN) ? K[(k * 2 + comp) * WLEN + j1] : 0.f;
    Kd2[idx] = packh(v0, v1);
}

// ---------------------------------------------------------------------------
// Pass 1 (MFMA): per block (t-tile of 512, n). 4 waves x 8 sixteen-t tiles.
// C[32][16] = A[32][128] x B[128][16], B[j][col] = x[tt + col + 50 - j].
// Reversed LDS: R[u] = x[t0 + CBOFF - u]; 8 shifted copies make every lane's
// 8-consecutive-K fragment a 16B-aligned ds_read_b128.
template <int STORE_C>
__global__ __launch_bounds__(256, 2) void k_conv(
        const float* __restrict__ X,
        const _Float16* __restrict__ Af,
        unsigned short* __restrict__ chs,
        float* __restrict__ sums,
        float* __restrict__ sumsq) {
    __shared__ __align__(16) _Float16 R[RLEN];
    __shared__ __align__(16) _Float16 RS[8][RLEN];
    __shared__ float red1[4][RANK], red2[4][RANK];
    const int n = blockIdx.y, tile = blockIdx.x, tid = threadIdx.x;
    const int t0 = tile * TILE;
    const float* Xn = X + (size_t)n * TLEN;

    for (int p = tid; p < RLEN; p += 256) {
        int xi = t0 + CBOFF - p;
        R[p] = (xi >= 0 && xi < TLEN) ? (_Float16)Xn[xi] : (_Float16)0.f;
    }
    __syncthreads();
#pragma unroll 1
    for (int s = 0; s < 8; ++s)
        for (int i = tid; i < RLEN; i += 256)
            RS[s][i] = (i + s < RLEN) ? R[i + s] : (_Float16)0.f;
    __syncthreads();

    const int lane = tid & 63, wid = tid >> 6;
    const int c = lane & 15, q0 = lane >> 4;
    const int s = (7 - c) & 7;
    const int ra = 2 * q0;                       // Mtile0 ranks ra, ra+1

    // A fragments: row = lane&15 (+16 for Mtile1), k = 32*ks + 8*q0 + e.
    const half8* Ap = (const half8*)Af;
    half8 a0[4], a1[4];
#pragma unroll
    for (int ks = 0; ks < 4; ++ks) {
        a0[ks] = Ap[c * 16 + 4 * ks + q0];
        a1[ks] = Ap[(16 + c) * 16 + 4 * ks + q0];
    }
    const half8* Bp = (const half8*)&RS[s][0];

    float sa0 = 0, sb0 = 0, sa1 = 0, sb1 = 0;
    float sa2 = 0, sb2 = 0, sa3 = 0, sb3 = 0;
#pragma unroll 1
    for (int it = 0; it < 8; ++it) {
        const int tau = wid * 8 + it;
        // u = (511 - 16*tau + 8*q0 - c) + 32*ks + e; subtract s -> mult of 8
        const int base8 = (511 - 16 * tau + 8 * q0 - c - s) >> 3;
        f32x4 acc0 = {0.f, 0.f, 0.f, 0.f};
        f32x4 acc1 = {0.f, 0.f, 0.f, 0.f};
#pragma unroll
        for (int ks = 0; ks < 4; ++ks) {
            half8 b = Bp[base8 + 4 * ks];
            acc0 = __builtin_amdgcn_mfma_f32_16x16x32_f16(a0[ks], b, acc0, 0, 0, 0);
            acc1 = __builtin_amdgcn_mfma_f32_16x16x32_f16(a1[ks], b, acc1, 0, 0, 0);
        }
        // C rows 4q0+r = (re,im) of ranks ra, ra+1; Mtile1 rows 16+4q0+r.
        float m00 = sqrtf(fmaf(acc0[0], acc0[0], acc0[1] * acc0[1]));
        float m01 = sqrtf(fmaf(acc0[2], acc0[2], acc0[3] * acc0[3]));
        float m10 = sqrtf(fmaf(acc1[0], acc1[0], acc1[1] * acc1[1]));
        float m11 = sqrtf(fmaf(acc1[2], acc1[2], acc1[3] * acc1[3]));
        int t = t0 + 16 * tau + c;
        float v0 = (t < TLEN) ? m00 : 0.f;
        float v1 = (t < TLEN) ? m01 : 0.f;
        float v2 = (t < TLEN) ? m10 : 0.f;
        float v3 = (t < TLEN) ? m11 : 0.f;
        sa0 += v0; sb0 = fmaf(v0, v0, sb0);
        sa1 += v1; sb1 = fmaf(v1, v1, sb1);
        sa2 += v2; sb2 = fmaf(v2, v2, sb2);
        sa3 += v3; sb3 = fmaf(v3, v3, sb3);
        if (STORE_C) {
            size_t tt = (size_t)t;
            chs[((size_t)(n * RANK + ra)) * TPAD + tt] = h16(m00);
            chs[((size_t)(n * RANK + ra + 1)) * TPAD + tt] = h16(m01);
            if (q0 == 0) {
                chs[((size_t)(n * RANK + 8)) * TPAD + tt] = h16(m10);
                chs[((size_t)(n * RANK + 9)) * TPAD + tt] = h16(m11);
            }
        }
    }
    // reduce over c (low 4 lane bits)
#pragma unroll
    for (int m = 1; m <= 8; m <<= 1) {
        sa0 += __shfl_xor(sa0, m); sb0 += __shfl_xor(sb0, m);
        sa1 += __shfl_xor(sa1, m); sb1 += __shfl_xor(sb1, m);
        sa2 += __shfl_xor(sa2, m); sb2 += __shfl_xor(sb2, m);
        sa3 += __shfl_xor(sa3, m); sb3 += __shfl_xor(sb3, m);
    }
    if (c == 0) {
        red1[wid][ra] = sa0;     red2[wid][ra] = sb0;
        red1[wid][ra + 1] = sa1; red2[wid][ra + 1] = sb1;
        if (q0 == 0) {
            red1[wid][8] = sa2; red2[wid][8] = sb2;
            red1[wid][9] = sa3; red2[wid][9] = sb3;
        }
    }
    __syncthreads();
    if (tid < RANK) {
        float a = red1[0][tid] + red1[1][tid] + red1[2][tid] + red1[3][tid];
        atomicAdd(&sums[n * RANK + tid], a);
    } else if (tid >= 64 && tid < 64 + RANK) {
        int k = tid - 64;
        float b = red2[0][k] + red2[1][k] + red2[2][k] + red2[3][k];
        atomicAdd(&sumsq[n * RANK + k], b);
    }
}

// ---------------------------------------------------------------------------
// Finalize: W[n,k] = B1/std,  bias2[m] = bias[m] - sum mean*W*B2.
__global__ void k_fin(const float* __restrict__ sums,
                      const float* __restrict__ sumsq,
                      const float* __restrict__ B1,
                      const float* __restrict__ B2,
                      const float* __restrict__ bias,
                      float* __restrict__ Wm,
                      float* __restrict__ bias2) {
    __shared__ float mw[NIN * RANK];
    int tid = threadIdx.x;
    for (int idx = tid; idx < NIN * RANK; idx += 256) {
        float s = sums[idx], s2 = sumsq[idx];
        float mean = s / (float)TLEN;
        float var = fmaxf((s2 - s * mean) / (float)(TLEN - 1), 1e-12f);
        float w = B1[idx] / sqrtf(var);
        Wm[idx] = w;
        mw[idx] = mean * w;
    }
    __syncthreads();
    if (tid < NOUT) {
        float acc = bias[tid];
        for (int n = 0; n < NIN; ++n)
#pragma unroll
            for (int k = 0; k < RANK; ++k)
                acc -= mw[n * RANK + k] * B2[k * NOUT + tid];
        bias2[tid] = acc;
    }
}

// ---------------------------------------------------------------------------
// Pass 2 (BIG): read f16 c, ypart[ch,k,t] over an n-chunk. grid (NTT, nch).
__global__ void k_comb(const unsigned* __restrict__ ch,
                       const float* __restrict__ Wm,
                       float* __restrict__ ypart, int npc) {
    __shared__ float wl[NIN * RANK / 4];
    int t2 = blockIdx.x * 256 + threadIdx.x;
    int chn = blockIdx.y, tid = threadIdx.x;
    int n0 = chn * npc;
    for (int idx = tid; idx < npc * RANK; idx += 256)
        wl[idx] = Wm[n0 * RANK + idx];
    __syncthreads();
    float2 y[RANK];
#pragma unroll
    for (int k = 0; k < RANK; ++k) y[k] = make_float2(0.f, 0.f);
    for (int nn = 0; nn < npc; ++nn) {
#pragma unroll
        for (int k = 0; k < RANK; ++k) {
            unsigned u = ch[((size_t)((n0 + nn) * RANK + k)) * (TPAD >> 1) + t2];
            h2 v = as_h2(u);
            float w = wl[nn * RANK + k];
            y[k].x = fmaf((float)v.x, w, y[k].x);
            y[k].y = fmaf((float)v.y, w, y[k].y);
        }
    }
#pragma unroll
    for (int k = 0; k < RANK; ++k)
        *(float2*)&ypart[((size_t)(chn * RANK + k)) * TPAD + 2 * t2] = y[k];
}

// ---------------------------------------------------------------------------
// Fallback conv core (fdot2), used only when ws can't hold c.
__device__ __forceinline__ void stage_Rp(const float* __restrict__ Xn,
                                         unsigned* Rs, int tstart) {
    for (int p = threadIdx.x; p < XS; p += 256) {
        int s = tstart - 55 + p;
        float x0 = (s >= 0 && s < TLEN) ? Xn[s] : 0.f;
        float x1 = (s + 1 >= 0 && s + 1 < TLEN) ? Xn[s + 1] : 0.f;
        Rs[p] = packh(x1, x0);
    }
}

__device__ __forceinline__ void conv_all(const unsigned* Rs, const unsigned* Kl,
                                         int tid,
                                         float (&re)[RANK][2],
                                         float (&im)[RANK][2]) {
#pragma unroll
    for (int k = 0; k < RANK; ++k) {
        re[k][0] = 0.f; re[k][1] = 0.f; im[k][0] = 0.f; im[k][1] = 0.f;
    }
    int pb = 2 * tid + 104;
#pragma unroll 1
    for (int ap = 0; ap < 25; ++ap) {
        int p = pb - 4 * ap;
        uint2 wA = *(const uint2*)&Rs[p];
        uint2 wB = *(const uint2*)&Rs[p - 2];
        h2 e0 = as_h2(wA.x), e1 = as_h2(wA.y);
        h2 o0 = as_h2(wB.x), o1 = as_h2(wB.y);
        const uint4* t0 = (const uint4*)&Kl[40 * ap];
        const uint4* t1 = (const uint4*)&Kl[40 * ap + 20];
#pragma unroll
        for (int kp = 0; kp < 5; ++kp) {
            const int k0 = 2 * kp, k1 = 2 * kp + 1;
            uint4 ta = t0[kp];
            h2 r0 = as_h2(ta.x), i0 = as_h2(ta.y);
            h2 r1 = as_h2(ta.z), i1 = as_h2(ta.w);
            re[k0][0] = FDOT2(e0, r0, re[k0][0]); im[k0][0] = FDOT2(e0, i0, im[k0][0]);
            re[k0][1] = FDOT2(e1, r0, re[k0][1]); im[k0][1] = FDOT2(e1, i0, im[k0][1]);
            re[k1][0] = FDOT2(e0, r1, re[k1][0]); im[k1][0] = FDOT2(e0, i1, im[k1][0]);
            re[k1][1] = FDOT2(e1, r1, re[k1][1]); im[k1][1] = FDOT2(e1, i1, im[k1][1]);
            uint4 tb = t1[kp];
            h2 s0 = as_h2(tb.x), j0 = as_h2(tb.y);
            h2 s1 = as_h2(tb.z), j1 = as_h2(tb.w);
            re[k0][0] = FDOT2(o0, s0, re[k0][0]); im[k0][0] = FDOT2(o0, j0, im[k0][0]);
            re[k0][1] = FDOT2(o1, s0, re[k0][1]); im[k0][1] = FDOT2(o1, j0, im[k0][1]);
            re[k1][0] = FDOT2(o0, s1, re[k1][0]); im[k1][0] = FDOT2(o0, j1, im[k1][0]);
            re[k1][1] = FDOT2(o1, s1, re[k1][1]); im[k1][1] = FDOT2(o1, j1, im[k1][1]);
        }
    }
    {
        int p = pb - 100;
        uint2 wA = *(const uint2*)&Rs[p];
        h2 e0 = as_h2(wA.x), e1 = as_h2(wA.y);
        const uint4* t0 = (const uint4*)&Kl[1000];
#pragma unroll
        for (int kp = 0; kp < 5; ++kp) {
            const int k0 = 2 * kp, k1 = 2 * kp + 1;
            uint4 ta = t0[kp];
            h2 r0 = as_h2(ta.x), i0 = as_h2(ta.y);
            h2 r1 = as_h2(ta.z), i1 = as_h2(ta.w);
            re[k0][0] = FDOT2(e0, r0, re[k0][0]); im[k0][0] = FDOT2(e0, i0, im[k0][0]);
            re[k0][1] = FDOT2(e1, r0, re[k0][1]); im[k0][1] = FDOT2(e1, i0, im[k0][1]);
            re[k1][0] = FDOT2(e0, r1, re[k1][0]); im[k1][0] = FDOT2(e0, i1, im[k1][0]);
            re[k1][1] = FDOT2(e1, r1, re[k1][1]); im[k1][1] = FDOT2(e1, i1, im[k1][1]);
        }
    }
}

// Pass 2 (SMALL fallback): recompute conv, accumulate over n-chunk.
__global__ __launch_bounds__(256, 4) void k_comb_re(const float* __restrict__ X,
                          const unsigned* __restrict__ Kd2,
                          const float* __restrict__ Wm,
                          float* __restrict__ ypart, int npc) {
    __shared__ __align__(16) unsigned Rs[XS];
    __shared__ __align__(16) unsigned Kl[KLDS];
    int chn = blockIdx.y, tile = blockIdx.x, tid = threadIdx.x;
    int tstart = tile * TILE;
    for (int idx = tid; idx < KLDS; idx += 256) Kl[idx] = Kd2[idx];
    float y[RANK][2];
#pragma unroll
    for (int k = 0; k < RANK; ++k) { y[k][0] = 0.f; y[k][1] = 0.f; }
    int n0 = chn * npc;
#pragma unroll 1
    for (int nn = 0; nn < npc; ++nn) {
        int n = n0 + nn;
        stage_Rp(X + (size_t)n * TLEN, Rs, tstart);
        __syncthreads();
        float re[RANK][2], im[RANK][2];
        conv_all(Rs, Kl, tid, re, im);
#pragma unroll
        for (int k = 0; k < RANK; ++k) {
            float w = Wm[n * RANK + k];
            float v0 = sqrtf(fmaf(re[k][0], re[k][0], im[k][0] * im[k][0]));
            float v1 = sqrtf(fmaf(re[k][1], re[k][1], im[k][1] * im[k][1]));
            y[k][0] = fmaf(v0, w, y[k][0]);
            y[k][1] = fmaf(v1, w, y[k][1]);
        }
        __syncthreads();
    }
    int tb = tstart + 2 * tid;
#pragma unroll
    for (int k = 0; k < RANK; ++k)
        *(float2*)&ypart[((size_t)(chn * RANK + k)) * TPAD + tb] =
            make_float2(y[k][0], y[k][1]);
}

// ---------------------------------------------------------------------------
// Final: out[m,t] = bias2[m] + sum_k B2[k,m] * sum_ch ypart[ch,k,t].
__global__ void k_out(const float* __restrict__ ypart,
                      const float* __restrict__ B2,
                      const float* __restrict__ bias2,
                      float* __restrict__ out, int nch) {
    int t2 = blockIdx.x * 256 + threadIdx.x;
    int t = 2 * t2;
    if (t >= TLEN) return;
    float2 y[RANK];
#pragma unroll
    for (int k = 0; k < RANK; ++k) y[k] = make_float2(0.f, 0.f);
    for (int chn = 0; chn < nch; ++chn) {
#pragma unroll
        for (int k = 0; k < RANK; ++k) {
            float2 v = *(const float2*)&ypart[((size_t)(chn * RANK + k)) * TPAD + t];
            y[k].x += v.x;
            y[k].y += v.y;
        }
    }
    for (int m = 0; m < NOUT; ++m) {
        float b = bias2[m];
        float2 acc = make_float2(b, b);
#pragma unroll
        for (int k = 0; k < RANK; ++k) {
            float w = B2[k * NOUT + m];
            acc.x = fmaf(y[k].x, w, acc.x);
            acc.y = fmaf(y[k].y, w, acc.y);
        }
        *(float2*)&out[(size_t)m * TLEN + t] = acc;
    }
}

// ---------------------------------------------------------------------------
extern "C" void kernel_launch(void* const* d_in, const int* in_sizes, int n_in,
                              void* d_out, int out_size, void* d_ws, size_t ws_size,
                              hipStream_t stream) {
    const float* X    = (const float*)d_in[0];
    const float* K    = (const float*)d_in[1];
    const float* B1   = (const float*)d_in[2];
    const float* B2   = (const float*)d_in[3];
    const float* bias = (const float*)d_in[4];
    float* out = (float*)d_out;

    char* p = (char*)d_ws;
    size_t off = 0;
    auto alloc = [&](size_t bytes) -> void* {
        void* r = p + off;
        off += (bytes + 255) & ~(size_t)255;
        return r;
    };
    float* sums  = (float*)alloc(NIN * RANK * sizeof(float));
    float* sumsq = (float*)alloc(NIN * RANK * sizeof(float));
    float* Wm    = (float*)alloc(NIN * RANK * sizeof(float));
    float* bias2 = (float*)alloc(NOUT * sizeof(float));
    unsigned* Kd2 = (unsigned*)alloc(KLDS * sizeof(unsigned));
    _Float16* Af  = (_Float16*)alloc(32 * 128 * sizeof(_Float16));

    size_t cbytes = (size_t)NIN * RANK * TPAD * sizeof(unsigned short); // 128.5 MB
    auto ypb = [](int n) {
        return (((size_t)n * RANK * TPAD * sizeof(float)) + 255) & ~(size_t)255;
    };

    int mode, nch;
    if (ws_size >= off + ypb(8) + cbytes)      { mode = 0; nch = 8; }
    else if (ws_size >= off + ypb(4) + cbytes) { mode = 0; nch = 4; }
    else if (ws_size >= off + ypb(8))          { mode = 1; nch = 8; }
    else                                       { mode = 1; nch = 1; }

    float* ypart = (float*)alloc((size_t)nch * RANK * TPAD * sizeof(float));
    unsigned short* c = (unsigned short*)(p + off);  // BIG path only

    hipMemsetAsync(sums, 0, 2 * NIN * RANK * sizeof(float), stream);

    k_prep_taps<<<dim3(16), 256, 0, stream>>>(K, Af);
    if (mode == 1)
        k_prep<<<dim3((KLDS + 255) / 256), 256, 0, stream>>>(K, Kd2);

    if (mode == 0)
        k_conv<1><<<dim3(NTT, NIN), 256, 0, stream>>>(X, Af, c, sums, sumsq);
    else
        k_conv<0><<<dim3(NTT, NIN), 256, 0, stream>>>(X, Af, c, sums, sumsq);

    k_fin<<<1, 256, 0, stream>>>(sums, sumsq, B1, B2, bias, Wm, bias2);

    if (mode == 0) {
        k_comb<<<dim3(NTT, nch), 256, 0, stream>>>((const unsigned*)c, Wm, ypart, NIN / nch);
    } else {
        k_comb_re<<<dim3(NTT, nch), 256, 0, stream>>>(X, Kd2, Wm, ypart, NIN / nch);
    }

    k_out<<<dim3(TPAD / 512), 256, 0, stream>>>(ypart, B2, bias2, out, nch);
}